// Round 10
// baseline (91.650 us; speedup 1.0000x reference)
//
#include <hip/hip_runtime.h>
#include <stdint.h>

typedef unsigned int u32;
typedef unsigned long long u64;
typedef int v4i  __attribute__((ext_vector_type(4)));
typedef int v16i __attribute__((ext_vector_type(16)));

// Binarized MLP via i8 MFMA: sign(x)@sign(w)^T with ±1 as int8 is an exact
// i32 dot -> v_mfma_i32_32x32x32_i8 (4404 TOPS, 8x the popcount VALU rate).
// K-pads are 0 in the WEIGHT i8 (0 * anything = 0), so act-side pad bits can
// be garbage. A-fragments are expanded on the fly from bit-packed acts via a
// 16-entry LDS nibble LUT (ds_read-fed -> no VALU->MFMA hazard). B streams
// through a double-buffered LDS pair, one barrier per k-step. BN epilogue =
// proven-exact op order (r1-r9, absmax=0); acts re-packed to bits by ballot.
// MFMA through inline asm (ISA mnemonic); A/B use the same e->k formula so
// any k-permutation in the HW layout cancels; C/D layout = m74/m101 formula.

#define NB    16384
#define DIN   784
#define HID   512
#define DOUT  10
#define MB    64          // rows per block; 256 blocks = 1/CU

// ws byte offsets
#define W1OFF 0           // [25 ks][2 kh][512 col][16] i8  (409600 B)
#define W2OFF 409600      // [16][2][512][16]               (262144 B)
#define W3OFF 671744      // [16][2][512][16]
#define W4OFF 933888      // [16][2][32 col][16], col>=10 zeroed (16384 B)
#define XPOFF 950272      // Xp u32[16384][26]: bit k of word ks = sign(x[r][ks*32+bit])
#define APOFF 2654208     // Apre f32[3][512] = g*(1/sqrt(v+eps)), bit-exact
#define XROW  26

// ---------------- pack: weights->i8, x->bits, BN scale ----------------
__global__ void bmlp_pack(const float* __restrict__ x,
                          const float* __restrict__ w1, const float* __restrict__ w2,
                          const float* __restrict__ w3, const float* __restrict__ w4,
                          const float* __restrict__ g1, const float* __restrict__ v1,
                          const float* __restrict__ g2, const float* __restrict__ v2,
                          const float* __restrict__ g3, const float* __restrict__ v3,
                          char* __restrict__ ws)
{
    const int tid = threadIdx.x, lane = tid & 63;
    if (blockIdx.x < 238) {                       // weight/Apre region (60928 threads)
        int tt = blockIdx.x * 256 + tid;
        const float* src; int base, K, dst16; bool zero = false;
        if (tt < 25600) {                         // W1
            int r = tt, ks = r >> 10, khh = (r >> 9) & 1, col = r & 511;
            base = ks * 32 + khh * 16; src = w1 + col * DIN; K = DIN; dst16 = r;
        } else if (tt < 41984) {                  // W2
            int r = tt - 25600, ks = r >> 10, khh = (r >> 9) & 1, col = r & 511;
            base = ks * 32 + khh * 16; src = w2 + col * HID; K = HID; dst16 = W2OFF / 16 + r;
        } else if (tt < 58368) {                  // W3
            int r = tt - 41984, ks = r >> 10, khh = (r >> 9) & 1, col = r & 511;
            base = ks * 32 + khh * 16; src = w3 + col * HID; K = HID; dst16 = W3OFF / 16 + r;
        } else if (tt < 59392) {                  // W4 (32-col padded, 10 real)
            int r = tt - 58368, ks = r >> 6, khh = (r >> 5) & 1, col = r & 31;
            base = ks * 32 + khh * 16; src = w4 + col * HID; K = HID; dst16 = W4OFF / 16 + r;
            zero = (col >= DOUT);
        } else {                                  // Apre
            int ai = tt - 59392;
            if (ai < 1536) {
                int ly = ai >> 9, c = ai & 511;
                const float* g = (ly == 0) ? g1 : (ly == 1) ? g2 : g3;
                const float* v = (ly == 0) ? v1 : (ly == 1) ? v2 : v3;
                float eps = (ly == 2) ? 512.0f : 1e-5f;   // EPS3 source bug: 512
                float A = __fmul_rn(g[c], __fdiv_rn(1.0f, __fsqrt_rn(__fadd_rn(v[c], eps))));
                ((float*)(ws + APOFF))[ai] = A;
            }
            return;
        }
        u32 d[4] = {0u, 0u, 0u, 0u};
        if (!zero) {
#pragma unroll
            for (int j = 0; j < 16; ++j) {
                int eg = base + j;
                u32 byte = 0;                     // K-pad -> 0 (kills act-pad garbage)
                if (eg < K) byte = (src[eg] < 0.0f) ? 0xFFu : 0x01u;   // -1 / +1
                d[j >> 2] |= byte << ((j & 3) * 8);
            }
        }
        v4i val; val.x = (int)d[0]; val.y = (int)d[1]; val.z = (int)d[2]; val.w = (int)d[3];
        ((v4i*)ws)[dst16] = val;
    } else {                                      // x bit-pack: wave per (row, 64-bit chunk)
        int wvi = (blockIdx.x - 238) * 4 + (tid >> 6);
        if (wvi >= NB * 13) return;
        int row = wvi / 13, j = wvi - row * 13;
        int e = j * 64 + lane;
        float v = (e < DIN) ? x[row * DIN + e] : 1.0f;    // pad bits 0 (unused anyway)
        u64 bal = __ballot(v < 0.0f);
        if (lane == 0) *(u64*)(ws + XPOFF + row * 104 + j * 8) = bal;
    }
}

// ---------------- fused MLP ----------------
// One k-step: barrier; load next B-slice to regs; prefetch next A-word;
// expand A (LUT); 4x MFMA from current LDS B; ds_write next B-slice.
template<int NK, bool ALDS>
__device__ __forceinline__ void klp(const char* __restrict__ Wsrc,
                                    const u32* asrc, int aswz,
                                    char* BbA, char* BbB, v16i* acc,
                                    const u32* lut, int tid, int lane, int q, int kh)
{
    const v4i* Wg4 = (const v4i*)Wsrc;
    {   // prologue: stage ks=0 into BbA (prior epilogue barrier makes this safe)
        v4i s0 = Wg4[tid], s1 = Wg4[512 + tid];
        *(v4i*)(BbA + tid * 16) = s0;
        *(v4i*)(BbA + 8192 + tid * 16) = s1;
    }
    u32 awc = ALDS ? asrc[0 ^ aswz] : asrc[0];
    const char* bb = (const char*)0;
#pragma unroll 1
    for (int ks = 0; ks < NK; ++ks) {
        __syncthreads();                          // drains vmcnt+lgkm: cur ready, prev reads done
        char* cur = (ks & 1) ? BbB : BbA;
        char* nxt = (ks & 1) ? BbA : BbB;
        v4i s0, s1; u32 awn = 0;
        const bool more = (ks + 1 < NK);
        if (more) {
            s0 = Wg4[(ks + 1) * 1024 + tid];
            s1 = Wg4[(ks + 1) * 1024 + 512 + tid];
            awn = ALDS ? asrc[(ks + 1) ^ aswz] : asrc[ks + 1];
        }
        u32 sel = kh ? (awc >> 16) : (awc & 0xFFFFu);
        v4i af;                                   // 16 i8 from 16 bits via LDS LUT
        af.x = (int)lut[sel & 15];
        af.y = (int)lut[(sel >> 4) & 15];
        af.z = (int)lut[(sel >> 8) & 15];
        af.w = (int)lut[(sel >> 12) & 15];
        bb = cur + (kh * 512 + q * 128 + (lane & 31)) * 16;
#pragma unroll
        for (int c = 0; c < 4; ++c) {
            v4i bf = *(const v4i*)(bb + c * 512);
            asm volatile("v_mfma_i32_32x32x32_i8 %0, %1, %2, %0"
                         : "+v"(acc[c]) : "v"(af), "v"(bf));
        }
        if (more) {
            *(v4i*)(nxt + tid * 16) = s0;         // vmcnt-waited by compiler
            *(v4i*)(nxt + 8192 + tid * 16) = s1;
        }
        awc = awn;
    }
}

// BN + sign -> ballot -> bit-packed acts (exact reference op order, r1-r9)
__device__ __forceinline__ void epilogue(v16i* acc, u32* dstA,
    const float* __restrict__ b, const float* __restrict__ m,
    const float* __restrict__ be, const float* __restrict__ Apl,
    int lane, int q, int mh)
{
    asm volatile("s_nop 7\ns_nop 7\ns_nop 7"      // MFMA->VALU read fence
                 : "+v"(acc[0]), "+v"(acc[1]), "+v"(acc[2]), "+v"(acc[3]));
#pragma unroll
    for (int c = 0; c < 4; ++c) {
        int col = q * 128 + c * 32 + (lane & 31);
        float pb = b[col], pm = m[col], pe = be[col], pA = Apl[col];
        int wn = q * 4 + c;
#pragma unroll
        for (int rg = 0; rg < 16; ++rg) {
            float dotf = (float)acc[c][rg];       // exact integer
            float xl = __fadd_rn(dotf, pb);
            float y  = __fadd_rn(__fmul_rn(__fsub_rn(xl, pm), pA), pe);
            u64 bal = __ballot(y < 0.0f);         // bit=1 <=> -1
            int r0 = mh * 32 + (rg & 3) + 8 * (rg >> 2), r1 = r0 + 4;
            if (lane == 0)  dstA[r0 * 16 + (wn ^ (r0 & 15))] = (u32)bal;
            if (lane == 32) dstA[r1 * 16 + (wn ^ (r1 & 15))] = (u32)(bal >> 32);
            acc[c][rg] = 0;                       // re-zero for next layer
        }
    }
    __syncthreads();
}

__global__ __launch_bounds__(512, 1)
void bmlp_mfma(const char* __restrict__ ws,
               const float* __restrict__ b1, const float* __restrict__ m1, const float* __restrict__ be1,
               const float* __restrict__ b2, const float* __restrict__ m2, const float* __restrict__ be2,
               const float* __restrict__ b3, const float* __restrict__ m3, const float* __restrict__ be3,
               const float* __restrict__ b4, float* __restrict__ out)
{
    __shared__ __align__(16) char Bb0[16384], Bb1[16384];   // B slice double buffer
    __shared__ __align__(16) u32 ActsA[1024], ActsB[1024];  // bit-packed acts [64][16], swizzled
    __shared__ u32 LUT[16];

    const int tid = threadIdx.x, lane = tid & 63;
    const int wv = tid >> 6, mh = wv >> 2, q = wv & 3;
    const int kh = lane >> 5;
    const int rowA = mh * 32 + (lane & 31);
    const int row0 = blockIdx.x * MB;

    if (tid < 16) {
        int n = tid;                               // nibble -> 4 i8 bytes (bit? -1 : +1)
        LUT[n] = ((n & 1) ? 0xFFu : 0x01u) | ((n & 2) ? 0xFF00u : 0x0100u)
               | ((n & 4) ? 0xFF0000u : 0x010000u) | ((n & 8) ? 0xFF000000u : 0x01000000u);
    }

    const u32* Xp  = (const u32*)(ws + XPOFF);
    const float* Ap = (const float*)(ws + APOFF);

    v16i acc[4];
#pragma unroll
    for (int c = 0; c < 4; ++c)
#pragma unroll
        for (int i = 0; i < 16; ++i) acc[c][i] = 0;

    // L1: A bits from global Xp (K=800 padded; weight pads are 0)
    klp<25, false>(ws + W1OFF, Xp + (row0 + rowA) * XROW, 0, Bb0, Bb1, acc, LUT, tid, lane, q, kh);
    epilogue(acc, ActsA, b1, m1, be1, Ap, lane, q, mh);
    // L2
    klp<16, true>(ws + W2OFF, ActsA + rowA * 16, rowA & 15, Bb0, Bb1, acc, LUT, tid, lane, q, kh);
    epilogue(acc, ActsB, b2, m2, be2, Ap + 512, lane, q, mh);
    // L3 (eps=512 folded into Apre)
    klp<16, true>(ws + W3OFF, ActsB + rowA * 16, rowA & 15, Bb0, Bb1, acc, LUT, tid, lane, q, kh);
    epilogue(acc, ActsA, b3, m3, be3, Ap + 1024, lane, q, mh);

    // L4: stage whole w4 (16 KB) into Bb0, then q==0 waves compute 32-col tile
    {
        const v4i* Wg4 = (const v4i*)(ws + W4OFF);
        v4i s0 = Wg4[tid], s1 = Wg4[512 + tid];
        *(v4i*)(Bb0 + tid * 16) = s0;
        *(v4i*)(Bb0 + 8192 + tid * 16) = s1;
    }
    __syncthreads();
    if (q == 0) {
        v16i a4;
#pragma unroll
        for (int i = 0; i < 16; ++i) a4[i] = 0;
        const u32* asrc = ActsA + rowA * 16;
        const int aswz = rowA & 15;
        u32 awc = asrc[0 ^ aswz];
#pragma unroll 1
        for (int ks = 0; ks < 16; ++ks) {
            u32 awn = (ks < 15) ? asrc[(ks + 1) ^ aswz] : 0;
            u32 sel = kh ? (awc >> 16) : (awc & 0xFFFFu);
            v4i af;
            af.x = (int)LUT[sel & 15];
            af.y = (int)LUT[(sel >> 4) & 15];
            af.z = (int)LUT[(sel >> 8) & 15];
            af.w = (int)LUT[(sel >> 12) & 15];
            v4i bf = *(const v4i*)(Bb0 + ks * 1024 + (kh * 32 + (lane & 31)) * 16);
            asm volatile("v_mfma_i32_32x32x32_i8 %0, %1, %2, %0"
                         : "+v"(a4) : "v"(af), "v"(bf));
            awc = awn;
        }
        asm volatile("s_nop 7\ns_nop 7\ns_nop 7" : "+v"(a4));
        int c = lane & 31;
        if (c < DOUT) {
            float pb = b4[c];
#pragma unroll
            for (int rg = 0; rg < 16; ++rg) {
                int rowE = mh * 32 + (rg & 3) + 8 * (rg >> 2) + 4 * kh;
                out[(row0 + rowE) * DOUT + c] = __fadd_rn((float)a4[rg], pb);
            }
        }
    }
}

extern "C" void kernel_launch(void* const* d_in, const int* in_sizes, int n_in,
                              void* d_out, int out_size, void* d_ws, size_t ws_size,
                              hipStream_t stream)
{
    const float* x   = (const float*)d_in[0];
    const float* w1  = (const float*)d_in[1];
    const float* b1  = (const float*)d_in[2];
    const float* g1  = (const float*)d_in[3];
    const float* be1 = (const float*)d_in[4];
    const float* m1  = (const float*)d_in[5];
    const float* v1  = (const float*)d_in[6];
    const float* w2  = (const float*)d_in[7];
    const float* b2  = (const float*)d_in[8];
    const float* g2  = (const float*)d_in[9];
    const float* be2 = (const float*)d_in[10];
    const float* m2  = (const float*)d_in[11];
    const float* v2  = (const float*)d_in[12];
    const float* w3  = (const float*)d_in[13];
    const float* b3  = (const float*)d_in[14];
    const float* g3  = (const float*)d_in[15];
    const float* be3 = (const float*)d_in[16];
    const float* m3  = (const float*)d_in[17];
    const float* v3  = (const float*)d_in[18];
    const float* w4  = (const float*)d_in[19];
    const float* b4  = (const float*)d_in[20];
    float* out = (float*)d_out;
    char* ws = (char*)d_ws;                 // ~2.66 MB used

    // pack: 238 weight blocks + 53248 x-pack blocks
    bmlp_pack<<<dim3(238 + NB * 13 / 4), 256, 0, stream>>>(
        x, w1, w2, w3, w4, g1, v1, g2, v2, g3, v3, ws);

    bmlp_mfma<<<dim3(NB / MB), 512, 0, stream>>>(
        ws,
        b1, m1, be1,
        b2, m2, be2,
        b3, m3, be3,
        b4, out);
}

// Round 11
// 84.149 us; speedup vs baseline: 1.0891x; 1.0891x over previous
//
#include <hip/hip_runtime.h>
#include <stdint.h>

typedef unsigned int u32;
typedef unsigned long long u64;
typedef int v4i  __attribute__((ext_vector_type(4)));
typedef int v16i __attribute__((ext_vector_type(16)));

// Binarized MLP via i8 MFMA (layouts PROVEN correct in r10, absmax=0).
// r11 fixes r10's two diseases:
//  (1) acc "+v" forced all 64 acc values into VGPRs (VGPR_Count=64!) ->
//      shuttle copies around every asm. Now "+a": ISA a-form
//      v_mfma_i32_32x32x32_i8 a[0:15], v[0:3], v[4:7], a[0:15]; acc lives
//      in AGPRs, VGPRs freed for operands/staging.
//  (2) per-step load->reg->vmcnt-drain->ds_write->barrier exposed ~300cy
//      L2 latency 57x. Now 2-deep: issue slice ks+2 loads at step ks,
//      ds_write them at step ks+1 (regs carry across the barrier) -> the
//      vmcnt wait has a full step of slack. Still 2 buffers, 1 barrier/step.

#define NB    16384
#define DIN   784
#define HID   512
#define DOUT  10
#define MB    64          // rows per block; 256 blocks = 1/CU

// ws byte offsets (identical to r10)
#define W1OFF 0           // [25 ks][2 kh][512 col][16] i8  (409600 B)
#define W2OFF 409600      // [16][2][512][16]               (262144 B)
#define W3OFF 671744      // [16][2][512][16]
#define W4OFF 933888      // [16][2][32 col][16], col>=10 zeroed (16384 B)
#define XPOFF 950272      // Xp u32[16384][26]
#define APOFF 2654208     // Apre f32[3][512] = g*(1/sqrt(v+eps)), bit-exact
#define XROW  26

// ---------------- pack: weights->i8, x->bits, BN scale (r10, proven) -----
__global__ void bmlp_pack(const float* __restrict__ x,
                          const float* __restrict__ w1, const float* __restrict__ w2,
                          const float* __restrict__ w3, const float* __restrict__ w4,
                          const float* __restrict__ g1, const float* __restrict__ v1,
                          const float* __restrict__ g2, const float* __restrict__ v2,
                          const float* __restrict__ g3, const float* __restrict__ v3,
                          char* __restrict__ ws)
{
    const int tid = threadIdx.x, lane = tid & 63;
    if (blockIdx.x < 238) {                       // weight/Apre region
        int tt = blockIdx.x * 256 + tid;
        const float* src; int base, K, dst16; bool zero = false;
        if (tt < 25600) {                         // W1
            int r = tt, ks = r >> 10, khh = (r >> 9) & 1, col = r & 511;
            base = ks * 32 + khh * 16; src = w1 + col * DIN; K = DIN; dst16 = r;
        } else if (tt < 41984) {                  // W2
            int r = tt - 25600, ks = r >> 10, khh = (r >> 9) & 1, col = r & 511;
            base = ks * 32 + khh * 16; src = w2 + col * HID; K = HID; dst16 = W2OFF / 16 + r;
        } else if (tt < 58368) {                  // W3
            int r = tt - 41984, ks = r >> 10, khh = (r >> 9) & 1, col = r & 511;
            base = ks * 32 + khh * 16; src = w3 + col * HID; K = HID; dst16 = W3OFF / 16 + r;
        } else if (tt < 59392) {                  // W4 (32-col padded, 10 real)
            int r = tt - 58368, ks = r >> 6, khh = (r >> 5) & 1, col = r & 31;
            base = ks * 32 + khh * 16; src = w4 + col * HID; K = HID; dst16 = W4OFF / 16 + r;
            zero = (col >= DOUT);
        } else {                                  // Apre
            int ai = tt - 59392;
            if (ai < 1536) {
                int ly = ai >> 9, c = ai & 511;
                const float* g = (ly == 0) ? g1 : (ly == 1) ? g2 : g3;
                const float* v = (ly == 0) ? v1 : (ly == 1) ? v2 : v3;
                float eps = (ly == 2) ? 512.0f : 1e-5f;   // EPS3 source bug: 512
                float A = __fmul_rn(g[c], __fdiv_rn(1.0f, __fsqrt_rn(__fadd_rn(v[c], eps))));
                ((float*)(ws + APOFF))[ai] = A;
            }
            return;
        }
        u32 d[4] = {0u, 0u, 0u, 0u};
        if (!zero) {
#pragma unroll
            for (int j = 0; j < 16; ++j) {
                int eg = base + j;
                u32 byte = 0;                     // K-pad -> 0 (kills act-pad garbage)
                if (eg < K) byte = (src[eg] < 0.0f) ? 0xFFu : 0x01u;   // -1 / +1
                d[j >> 2] |= byte << ((j & 3) * 8);
            }
        }
        v4i val; val.x = (int)d[0]; val.y = (int)d[1]; val.z = (int)d[2]; val.w = (int)d[3];
        ((v4i*)ws)[dst16] = val;
    } else {                                      // x bit-pack
        int wvi = (blockIdx.x - 238) * 4 + (tid >> 6);
        if (wvi >= NB * 13) return;
        int row = wvi / 13, j = wvi - row * 13;
        int e = j * 64 + lane;
        float v = (e < DIN) ? x[row * DIN + e] : 1.0f;    // pad bits 0
        u64 bal = __ballot(v < 0.0f);
        if (lane == 0) *(u64*)(ws + XPOFF + row * 104 + j * 8) = bal;
    }
}

// ---------------- fused MLP ----------------
// 2-deep pipelined k-loop. Step ks: barrier; ds_write slice ks+1 (regs
// loaded at step ks-1 -> vmcnt has a full step of slack); issue loads for
// slice ks+2; expand A (LUT); 4x MFMA from buf[ks&1].
template<int NK, bool ALDS>
__device__ __forceinline__ void klp(const char* __restrict__ Wsrc,
                                    const u32* asrc, int aswz,
                                    char* BbA, char* BbB, v16i* acc,
                                    const u32* lut, int tid, int lane, int q, int kh)
{
    const v4i* Wg4 = (const v4i*)Wsrc;
    {   // prologue: slice 0 -> BbA directly (prior barrier makes this safe)
        v4i s0 = Wg4[tid], s1 = Wg4[512 + tid];
        *(v4i*)(BbA + tid * 16) = s0;
        *(v4i*)(BbA + 8192 + tid * 16) = s1;
    }
    v4i p0, p1;                                   // in-flight slice ks+1
    if (NK > 1) { p0 = Wg4[1024 + tid]; p1 = Wg4[1024 + 512 + tid]; }
    u32 awc = ALDS ? asrc[0 ^ aswz] : asrc[0];
    u32 awn = (NK > 1) ? (ALDS ? asrc[1 ^ aswz] : asrc[1]) : 0;

#pragma unroll 1
    for (int ks = 0; ks < NK; ++ks) {
        __syncthreads();                          // buf[ks&1] ready; prev reads done
        char* cur = (ks & 1) ? BbB : BbA;
        char* nxt = (ks & 1) ? BbA : BbB;
        if (ks + 1 < NK) {                        // write slice ks+1 (regs from step ks-1)
            *(v4i*)(nxt + tid * 16) = p0;
            *(v4i*)(nxt + 8192 + tid * 16) = p1;
        }
        if (ks + 2 < NK) {                        // issue loads for slice ks+2
            p0 = Wg4[(ks + 2) * 1024 + tid];
            p1 = Wg4[(ks + 2) * 1024 + 512 + tid];
        }
        u32 sel = kh ? (awc >> 16) : (awc & 0xFFFFu);
        v4i af;                                   // 16 i8 from 16 bits via LDS LUT
        af.x = (int)lut[sel & 15];
        af.y = (int)lut[(sel >> 4) & 15];
        af.z = (int)lut[(sel >> 8) & 15];
        af.w = (int)lut[(sel >> 12) & 15];
        awc = awn;
        if (ks + 2 < NK) awn = ALDS ? asrc[(ks + 2) ^ aswz] : asrc[ks + 2];
        const char* bb = cur + (kh * 512 + q * 128 + (lane & 31)) * 16;
#pragma unroll
        for (int c = 0; c < 4; ++c) {
            v4i bf = *(const v4i*)(bb + c * 512);
            asm("v_mfma_i32_32x32x32_i8 %0, %1, %2, %0"
                : "+a"(acc[c]) : "v"(af), "v"(bf));
        }
    }
}

// BN + sign -> ballot -> bit-packed acts (exact reference op order, proven)
__device__ __forceinline__ void epilogue(v16i* acc, u32* dstA,
    const float* __restrict__ b, const float* __restrict__ m,
    const float* __restrict__ be, const float* __restrict__ Apl,
    int lane, int q, int mh)
{
    asm volatile("s_nop 7\ns_nop 7\ns_nop 7"      // MFMA->read hazard fence
                 : "+a"(acc[0]), "+a"(acc[1]), "+a"(acc[2]), "+a"(acc[3]));
#pragma unroll
    for (int c = 0; c < 4; ++c) {
        int col = q * 128 + c * 32 + (lane & 31);
        float pb = b[col], pm = m[col], pe = be[col], pA = Apl[col];
        int wn = q * 4 + c;
#pragma unroll
        for (int rg = 0; rg < 16; ++rg) {
            float dotf = (float)acc[c][rg];       // exact integer
            float xl = __fadd_rn(dotf, pb);
            float y  = __fadd_rn(__fmul_rn(__fsub_rn(xl, pm), pA), pe);
            u64 bal = __ballot(y < 0.0f);         // bit=1 <=> -1
            int r0 = mh * 32 + (rg & 3) + 8 * (rg >> 2), r1 = r0 + 4;
            if (lane == 0)  dstA[r0 * 16 + (wn ^ (r0 & 15))] = (u32)bal;
            if (lane == 32) dstA[r1 * 16 + (wn ^ (r1 & 15))] = (u32)(bal >> 32);
            acc[c][rg] = 0;                       // re-zero for next layer
        }
    }
    __syncthreads();
}

__global__ __launch_bounds__(512, 1)
void bmlp_mfma(const char* __restrict__ ws,
               const float* __restrict__ b1, const float* __restrict__ m1, const float* __restrict__ be1,
               const float* __restrict__ b2, const float* __restrict__ m2, const float* __restrict__ be2,
               const float* __restrict__ b3, const float* __restrict__ m3, const float* __restrict__ be3,
               const float* __restrict__ b4, float* __restrict__ out)
{
    __shared__ __align__(16) char Bb0[16384], Bb1[16384];   // B slice double buffer
    __shared__ __align__(16) u32 ActsA[1024], ActsB[1024];  // bit-packed acts, swizzled
    __shared__ u32 LUT[16];

    const int tid = threadIdx.x, lane = tid & 63;
    const int wv = tid >> 6, mh = wv >> 2, q = wv & 3;
    const int kh = lane >> 5;
    const int rowA = mh * 32 + (lane & 31);
    const int row0 = blockIdx.x * MB;

    if (tid < 16) {
        int n = tid;                               // nibble -> 4 i8 bytes (bit? -1 : +1)
        LUT[n] = ((n & 1) ? 0xFFu : 0x01u) | ((n & 2) ? 0xFF00u : 0x0100u)
               | ((n & 4) ? 0xFF0000u : 0x010000u) | ((n & 8) ? 0xFF000000u : 0x01000000u);
    }

    const u32* Xp  = (const u32*)(ws + XPOFF);
    const float* Ap = (const float*)(ws + APOFF);

    v16i acc[4];
#pragma unroll
    for (int c = 0; c < 4; ++c)
#pragma unroll
        for (int i = 0; i < 16; ++i) acc[c][i] = 0;

    // L1: A bits from global Xp (K=800 padded; weight pads are 0)
    klp<25, false>(ws + W1OFF, Xp + (row0 + rowA) * XROW, 0, Bb0, Bb1, acc, LUT, tid, lane, q, kh);
    epilogue(acc, ActsA, b1, m1, be1, Ap, lane, q, mh);
    // L2
    klp<16, true>(ws + W2OFF, ActsA + rowA * 16, rowA & 15, Bb0, Bb1, acc, LUT, tid, lane, q, kh);
    epilogue(acc, ActsB, b2, m2, be2, Ap + 512, lane, q, mh);
    // L3 (eps=512 folded into Apre)
    klp<16, true>(ws + W3OFF, ActsB + rowA * 16, rowA & 15, Bb0, Bb1, acc, LUT, tid, lane, q, kh);
    epilogue(acc, ActsA, b3, m3, be3, Ap + 1024, lane, q, mh);

    // L4: stage whole w4 (16 KB) into Bb0, then q==0 waves compute 32-col tile
    {
        const v4i* Wg4 = (const v4i*)(ws + W4OFF);
        v4i s0 = Wg4[tid], s1 = Wg4[512 + tid];
        *(v4i*)(Bb0 + tid * 16) = s0;
        *(v4i*)(Bb0 + 8192 + tid * 16) = s1;
    }
    __syncthreads();
    if (q == 0) {
        v16i a4;
#pragma unroll
        for (int i = 0; i < 16; ++i) a4[i] = 0;
        const u32* asrc = ActsA + rowA * 16;
        const int aswz = rowA & 15;
        u32 awc = asrc[0 ^ aswz];
#pragma unroll 1
        for (int ks = 0; ks < 16; ++ks) {
            u32 awn = (ks < 15) ? asrc[(ks + 1) ^ aswz] : 0;
            u32 sel = kh ? (awc >> 16) : (awc & 0xFFFFu);
            v4i af;
            af.x = (int)LUT[sel & 15];
            af.y = (int)LUT[(sel >> 4) & 15];
            af.z = (int)LUT[(sel >> 8) & 15];
            af.w = (int)LUT[(sel >> 12) & 15];
            v4i bf = *(const v4i*)(Bb0 + ks * 1024 + (kh * 32 + (lane & 31)) * 16);
            asm("v_mfma_i32_32x32x32_i8 %0, %1, %2, %0"
                : "+a"(a4) : "v"(af), "v"(bf));
            awc = awn;
        }
        asm volatile("s_nop 7\ns_nop 7\ns_nop 7" : "+a"(a4));
        int c = lane & 31;
        if (c < DOUT) {
            float pb = b4[c];
#pragma unroll
            for (int rg = 0; rg < 16; ++rg) {
                int rowE = mh * 32 + (rg & 3) + 8 * (rg >> 2) + 4 * kh;
                out[(row0 + rowE) * DOUT + c] = __fadd_rn((float)a4[rg], pb);
            }
        }
    }
}

extern "C" void kernel_launch(void* const* d_in, const int* in_sizes, int n_in,
                              void* d_out, int out_size, void* d_ws, size_t ws_size,
                              hipStream_t stream)
{
    const float* x   = (const float*)d_in[0];
    const float* w1  = (const float*)d_in[1];
    const float* b1  = (const float*)d_in[2];
    const float* g1  = (const float*)d_in[3];
    const float* be1 = (const float*)d_in[4];
    const float* m1  = (const float*)d_in[5];
    const float* v1  = (const float*)d_in[6];
    const float* w2  = (const float*)d_in[7];
    const float* b2  = (const float*)d_in[8];
    const float* g2  = (const float*)d_in[9];
    const float* be2 = (const float*)d_in[10];
    const float* m2  = (const float*)d_in[11];
    const float* v2  = (const float*)d_in[12];
    const float* w3  = (const float*)d_in[13];
    const float* b3  = (const float*)d_in[14];
    const float* g3  = (const float*)d_in[15];
    const float* be3 = (const float*)d_in[16];
    const float* m3  = (const float*)d_in[17];
    const float* v3  = (const float*)d_in[18];
    const float* w4  = (const float*)d_in[19];
    const float* b4  = (const float*)d_in[20];
    float* out = (float*)d_out;
    char* ws = (char*)d_ws;                 // ~2.66 MB used

    bmlp_pack<<<dim3(238 + NB * 13 / 4), 256, 0, stream>>>(
        x, w1, w2, w3, w4, g1, v1, g2, v2, g3, v3, ws);

    bmlp_mfma<<<dim3(NB / MB), 512, 0, stream>>>(
        ws,
        b1, m1, be1,
        b2, m2, be2,
        b3, m3, be3,
        b4, out);
}

// Round 13
// 61.545 us; speedup vs baseline: 1.4892x; 1.3673x over previous
//
#include <hip/hip_runtime.h>
#include <stdint.h>

typedef unsigned int u32;
typedef unsigned long long u64;
typedef int v4i  __attribute__((ext_vector_type(4)));
typedef int v16i __attribute__((ext_vector_type(16)));

// Binarized MLP via i8 MFMA on 0/1 bytes (bit-algebra):
//   a=1-2alpha, b=1-2beta  =>  dot = K - 2*cntA(row) - 2*cntB(col) + 4*sum(alpha*beta)
// r13 = r12 + two fixes:
//  (1) epilogue read CNT[r0] for ALL lanes; hi-lanes (lane>=32) hold C/D rows
//      r0+4 -> wrong cntA subtracted. Now rowMe = r0 + ((lane&32)>>3).
//  (2) VALU-writes-VGPR -> MFMA-reads-SrcA/B needs manual wait states; the
//      compiler can't see through opaque inline-asm MFMA to insert them
//      (r10/r11 fed MFMA from ds_read results - path never exercised).
//      Now "s_nop 2" inside the MFMA asm. Explains absmax 5914 > max valid
//      error (~2000): acc itself was corrupted.

#define NB   16384
#define DIN  784
#define HID  512
#define DOUT 10
#define THR  512

// ws layout in u32 units
#define W1W 0        // [25][512] bit-words
#define W2W 12800    // [16][512]
#define W3W 20992    // [16][512]
#define W4W 29184    // [16][32]
#define D1W 29696    // int[512] = K - 2*cntB
#define D2W 30208
#define D3W 30720
#define D4W 31232    // int[32]
#define APW 31264    // float[3][512] = g*(1/sqrt(v+eps)), bit-exact
#define XPW 32800    // u32[16384][26] act bit-words

// ---------------- pack: bits + cntB + Apre (r12, logic verified) ----------
__global__ void bmlp_pack(const float* __restrict__ x,
                          const float* __restrict__ w1, const float* __restrict__ w2,
                          const float* __restrict__ w3, const float* __restrict__ w4,
                          const float* __restrict__ g1, const float* __restrict__ v1,
                          const float* __restrict__ g2, const float* __restrict__ v2,
                          const float* __restrict__ g3, const float* __restrict__ v3,
                          u32* __restrict__ ws)
{
    int gw = blockIdx.x * 4 + (int)(threadIdx.x >> 6);
    int lane = threadIdx.x & 63;

    if (gw < NB) {                              // x row -> 26 bit-words
        const float* xr = x + (size_t)gw * DIN;
        u64* dst = (u64*)(ws + XPW + gw * 26);
#pragma unroll
        for (int j = 0; j < 13; ++j) {
            int e = j * 64 + lane;
            float v = (e < DIN) ? xr[e] : 1.0f;     // pad bit 0
            u64 bal = __ballot(v < 0.0f);
            if (lane == 0) dst[j] = bal;
        }
        return;
    }
    gw -= NB;
    if (gw < 512 * 13) {                        // W1 bits [25][512]
        int col = gw / 13, k2 = gw - col * 13;
        int e = k2 * 64 + lane;
        float v = (e < DIN) ? w1[col * DIN + e] : 1.0f;
        u64 bal = __ballot(v < 0.0f);
        if (lane == 0) {
            ws[W1W + (2 * k2) * 512 + col] = (u32)bal;
            if (2 * k2 + 1 < 25) ws[W1W + (2 * k2 + 1) * 512 + col] = (u32)(bal >> 32);
        }
        return;
    }
    gw -= 512 * 13;
    if (gw < 512 * 8) {                         // W2 bits [16][512]
        int col = gw >> 3, k2 = gw & 7;
        u64 bal = __ballot(w2[col * HID + k2 * 64 + lane] < 0.0f);
        if (lane == 0) {
            ws[W2W + (2 * k2) * 512 + col]     = (u32)bal;
            ws[W2W + (2 * k2 + 1) * 512 + col] = (u32)(bal >> 32);
        }
        return;
    }
    gw -= 512 * 8;
    if (gw < 512 * 8) {                         // W3 bits
        int col = gw >> 3, k2 = gw & 7;
        u64 bal = __ballot(w3[col * HID + k2 * 64 + lane] < 0.0f);
        if (lane == 0) {
            ws[W3W + (2 * k2) * 512 + col]     = (u32)bal;
            ws[W3W + (2 * k2 + 1) * 512 + col] = (u32)(bal >> 32);
        }
        return;
    }
    gw -= 512 * 8;
    if (gw < 32 * 8) {                          // W4 bits [16][32] (cols>=10 zero)
        int col = gw >> 3, k2 = gw & 7;
        float v = (col < DOUT) ? w4[col * HID + k2 * 64 + lane] : 1.0f;
        u64 bal = __ballot(v < 0.0f);
        if (lane == 0) {
            ws[W4W + (2 * k2) * 32 + col]     = (u32)bal;
            ws[W4W + (2 * k2 + 1) * 32 + col] = (u32)(bal >> 32);
        }
        return;
    }
    gw -= 32 * 8;
    if (gw < 512) {                             // D0 layer1 = 784 - 2*cntB
        int col = gw, cnt = 0;
#pragma unroll
        for (int k2 = 0; k2 < 13; ++k2) {
            int e = k2 * 64 + lane;
            float v = (e < DIN) ? w1[col * DIN + e] : 1.0f;
            cnt += (int)__popcll(__ballot(v < 0.0f));
        }
        if (lane == 0) ((int*)ws)[D1W + col] = DIN - 2 * cnt;
        return;
    }
    gw -= 512;
    if (gw < 512) {                             // D0 layer2
        int col = gw, cnt = 0;
#pragma unroll
        for (int k2 = 0; k2 < 8; ++k2)
            cnt += (int)__popcll(__ballot(w2[col * HID + k2 * 64 + lane] < 0.0f));
        if (lane == 0) ((int*)ws)[D2W + col] = HID - 2 * cnt;
        return;
    }
    gw -= 512;
    if (gw < 512) {                             // D0 layer3
        int col = gw, cnt = 0;
#pragma unroll
        for (int k2 = 0; k2 < 8; ++k2)
            cnt += (int)__popcll(__ballot(w3[col * HID + k2 * 64 + lane] < 0.0f));
        if (lane == 0) ((int*)ws)[D3W + col] = HID - 2 * cnt;
        return;
    }
    gw -= 512;
    if (gw < 32) {                              // D0 layer4 (32 cols)
        int col = gw, cnt = 0;
#pragma unroll
        for (int k2 = 0; k2 < 8; ++k2) {
            float v = (col < DOUT) ? w4[col * HID + k2 * 64 + lane] : 1.0f;
            cnt += (int)__popcll(__ballot(v < 0.0f));
        }
        if (lane == 0) ((int*)ws)[D4W + col] = HID - 2 * cnt;
        return;
    }
    gw -= 32;
    if (gw < 24) {                              // Apre, bit-exact
        int idx = gw * 64 + lane;
        int ly = idx >> 9, c = idx & 511;
        const float* g = (ly == 0) ? g1 : (ly == 1) ? g2 : g3;
        const float* v = (ly == 0) ? v1 : (ly == 1) ? v2 : v3;
        float eps = (ly == 2) ? 512.0f : 1e-5f;     // EPS3 source bug: 512
        float A = __fmul_rn(g[c], __fdiv_rn(1.0f, __fsqrt_rn(__fadd_rn(v[c], eps))));
        ((float*)ws)[APW + idx] = A;
    }
}

// ---------------- fused MLP ----------------
__device__ __forceinline__ v4i expand01(u32 sel)    // 16 bits -> 16 bytes 0/1
{
    v4i r;
    r.x = (int)((((sel      ) & 15u) * 0x00204081u) & 0x01010101u);
    r.y = (int)((((sel >> 4 ) & 15u) * 0x00204081u) & 0x01010101u);
    r.z = (int)((((sel >> 8 ) & 15u) * 0x00204081u) & 0x01010101u);
    r.w = (int)((((sel >> 12) & 15u) * 0x00204081u) & 0x01010101u);
    return r;
}

// s_nop 2 covers the VALU-write -> MFMA-read-SrcA/B manual wait states that
// the compiler cannot insert around opaque inline asm (r12 corruption).
__device__ __forceinline__ void mfma(v16i& a, v4i af, v4i bf)
{
    asm("s_nop 2\n\tv_mfma_i32_32x32x32_i8 %0, %1, %2, %0"
        : "+a"(a) : "v"(af), "v"(bf));
}

// K-loop over NK 32-wide slices. 2 A-frags (rows l31, l31+32) x 2 B-frags
// (cols wv*64+l31, +32) -> 4 MFMA/step. 4 conflict-free ds_read_b32/step.
template<int NK>
__device__ __forceinline__ void kloop(const u32* a0p, const u32* a1p,
                                      const u32* w0p, const u32* w1p,
                                      int kh16, v16i acc[2][2],
                                      u32& cA0, u32& cA1)
{
#pragma unroll
    for (int k = 0; k < NK; ++k) {
        u32 aw0 = a0p[k], aw1 = a1p[k];
        u32 bw0 = w0p[k], bw1 = w1p[k];
        cA0 += __popc(aw0); cA1 += __popc(aw1);     // full-word: kh-independent
        u32 sa0 = (aw0 >> kh16) & 0xFFFFu;
        u32 sa1 = (aw1 >> kh16) & 0xFFFFu;
        u32 sb0 = (bw0 >> kh16) & 0xFFFFu;
        u32 sb1 = (bw1 >> kh16) & 0xFFFFu;
        v4i af0 = expand01(sa0), af1 = expand01(sa1);
        v4i bf0 = expand01(sb0), bf1 = expand01(sb1);
        mfma(acc[0][0], af0, bf0); mfma(acc[0][1], af0, bf1);
        mfma(acc[1][0], af1, bf0); mfma(acc[1][1], af1, bf1);
    }
}

// BN + sign -> ballot -> bit-packed acts. Exact reference op order:
// dotI = (K-2cntB) - 2cntA(rowMe) + 4*acc (ints, exact); xl=dot+b;
// y=((xl-m)*A)+be. C/D row for THIS lane = r0 + 4*(lane>>5)  [r13 fix].
__device__ __forceinline__ void epilogue(v16i acc[2][2], u32* dst,
    const u32* CNT, const int* D0, const float* __restrict__ b,
    const float* __restrict__ m, const float* __restrict__ be,
    const float* __restrict__ Ap, int lane, int wv)
{
    asm volatile("s_nop 7\ns_nop 7\ns_nop 7"        // MFMA->read fence
        : "+a"(acc[0][0]), "+a"(acc[0][1]), "+a"(acc[1][0]), "+a"(acc[1][1]));
    const int l31 = lane & 31;
    const int rAdd = (lane & 32) >> 3;              // +4 for hi lanes
    int D0c[2]; float pb[2], pm[2], pe[2], pA[2];
#pragma unroll
    for (int c = 0; c < 2; ++c) {
        int col = wv * 64 + c * 32 + l31;
        D0c[c] = D0[col]; pb[c] = b[col]; pm[c] = m[col];
        pe[c] = be[col];  pA[c] = Ap[col];
    }
#pragma unroll
    for (int f = 0; f < 2; ++f)
#pragma unroll
        for (int rg = 0; rg < 16; ++rg) {
            int r0 = f * 32 + (rg & 3) + 8 * (rg >> 2);
            int rowMe = r0 + rAdd;                  // THIS lane's C/D row
            int s2 = 2 * (int)CNT[rowMe];
#pragma unroll
            for (int c = 0; c < 2; ++c) {
                int dotI = D0c[c] - s2 + 4 * acc[f][c][rg];
                float xl = __fadd_rn((float)dotI, pb[c]);
                float y  = __fadd_rn(__fmul_rn(__fsub_rn(xl, pm[c]), pA[c]), pe[c]);
                u64 bal = __ballot(y < 0.0f);       // bit=1 <=> -1
                if (!(lane & 31))                   // lanes 0 and 32
                    dst[rowMe * 17 + (wv * 2 + c)] = (u32)(bal >> ((lane >> 5) << 5));
                acc[f][c][rg] = 0;
            }
        }
}

__global__ __launch_bounds__(THR)
void bmlp_bits(const u32* __restrict__ ws,
               const float* __restrict__ b1, const float* __restrict__ m1, const float* __restrict__ be1,
               const float* __restrict__ b2, const float* __restrict__ m2, const float* __restrict__ be2,
               const float* __restrict__ b3, const float* __restrict__ m3, const float* __restrict__ be3,
               const float* __restrict__ b4, float* __restrict__ out)
{
    __shared__ u32 Wb[512 * 15];        // layer bit-words, stride 15 (odd)
    __shared__ u32 A1s[64 * 27];        // L1 acts, stride 27 (odd)
    __shared__ u32 AA[64 * 17];         // L1/L3 out acts, stride 17
    __shared__ u32 AB[64 * 17];         // L2 out acts
    __shared__ u32 CNT[64];             // per-row act popcounts

    const int tid = threadIdx.x, lane = tid & 63, wv = tid >> 6;
    const int l31 = lane & 31;
    const int kh16 = (lane & 32) >> 1;              // 0 / 16
    const int row0 = blockIdx.x * 64;
    const int col0 = wv * 64 + l31, col1 = col0 + 32;

    const float* Ap = (const float*)(ws + APW);
    const u32* Xpg = ws + XPW;
    const u32* wb0 = Wb + col0 * 15;
    const u32* wb1 = Wb + col1 * 15;

    // stage acts1 + W1 phase0 (coalesced; odd-stride LDS writes conflict-free)
    for (int i = tid; i < 64 * 26; i += THR) {
        int r = i / 26, wd = i - r * 26;
        A1s[r * 27 + wd] = Xpg[(size_t)(row0 + r) * 26 + wd];
    }
    for (int i = tid; i < 512 * 13; i += THR) {
        int ks = i >> 9, col = i & 511;
        Wb[col * 15 + ks] = ws[W1W + ks * 512 + col];
    }
    __syncthreads();

    v16i acc[2][2];
#pragma unroll
    for (int f = 0; f < 2; ++f)
#pragma unroll
        for (int c = 0; c < 2; ++c)
#pragma unroll
            for (int i = 0; i < 16; ++i) acc[f][c][i] = 0;
    u32 cA0 = 0, cA1 = 0;

    // ---- L1 (K=784+pads, 25 slices in 2 stages) ----
    kloop<13>(A1s + l31 * 27, A1s + (l31 + 32) * 27, wb0, wb1, kh16, acc, cA0, cA1);
    __syncthreads();
    for (int i = tid; i < 512 * 12; i += THR) {
        int ks = i >> 9, col = i & 511;
        Wb[col * 15 + ks] = ws[W1W + (13 + ks) * 512 + col];
    }
    __syncthreads();
    kloop<12>(A1s + l31 * 27 + 13, A1s + (l31 + 32) * 27 + 13, wb0, wb1, kh16, acc, cA0, cA1);
    if (wv == 0 && lane < 32) { CNT[lane] = cA0; CNT[lane + 32] = cA1; }
    __syncthreads();
    epilogue(acc, AA, CNT, (const int*)ws + D1W, b1, m1, be1, Ap, lane, wv);
    cA0 = cA1 = 0;
    __syncthreads();

    // ---- L2 (16 slices, 2 stages) ----
    for (int i = tid; i < 512 * 8; i += THR) {
        int ks = i >> 9, col = i & 511;
        Wb[col * 15 + ks] = ws[W2W + ks * 512 + col];
    }
    __syncthreads();
    kloop<8>(AA + l31 * 17, AA + (l31 + 32) * 17, wb0, wb1, kh16, acc, cA0, cA1);
    __syncthreads();
    for (int i = tid; i < 512 * 8; i += THR) {
        int ks = i >> 9, col = i & 511;
        Wb[col * 15 + ks] = ws[W2W + (8 + ks) * 512 + col];
    }
    __syncthreads();
    kloop<8>(AA + l31 * 17 + 8, AA + (l31 + 32) * 17 + 8, wb0, wb1, kh16, acc, cA0, cA1);
    if (wv == 0 && lane < 32) { CNT[lane] = cA0; CNT[lane + 32] = cA1; }
    __syncthreads();
    epilogue(acc, AB, CNT, (const int*)ws + D2W, b2, m2, be2, Ap + 512, lane, wv);
    cA0 = cA1 = 0;
    __syncthreads();

    // ---- L3 (eps=512 folded into Apre) ----
    for (int i = tid; i < 512 * 8; i += THR) {
        int ks = i >> 9, col = i & 511;
        Wb[col * 15 + ks] = ws[W3W + ks * 512 + col];
    }
    __syncthreads();
    kloop<8>(AB + l31 * 17, AB + (l31 + 32) * 17, wb0, wb1, kh16, acc, cA0, cA1);
    __syncthreads();
    for (int i = tid; i < 512 * 8; i += THR) {
        int ks = i >> 9, col = i & 511;
        Wb[col * 15 + ks] = ws[W3W + (8 + ks) * 512 + col];
    }
    __syncthreads();
    kloop<8>(AB + l31 * 17 + 8, AB + (l31 + 32) * 17 + 8, wb0, wb1, kh16, acc, cA0, cA1);
    if (wv == 0 && lane < 32) { CNT[lane] = cA0; CNT[lane + 32] = cA1; }
    __syncthreads();
    epilogue(acc, AA, CNT, (const int*)ws + D3W, b3, m3, be3, Ap + 1024, lane, wv);
    __syncthreads();                                 // AA complete before L4

    // ---- L4: wave 0 only; out = dot + b4 ----
    if (wv == 0) {
        u32 c40 = 0, c41 = 0;
#pragma unroll
        for (int ks = 0; ks < 16; ++ks) {
            u32 aw0 = AA[l31 * 17 + ks], aw1 = AA[(l31 + 32) * 17 + ks];
            u32 bw = ws[W4W + ks * 32 + l31];        // L2-hot global
            c40 += __popc(aw0); c41 += __popc(aw1);
            v4i af0 = expand01((aw0 >> kh16) & 0xFFFFu);
            v4i af1 = expand01((aw1 >> kh16) & 0xFFFFu);
            v4i bf  = expand01((bw  >> kh16) & 0xFFFFu);
            mfma(acc[0][0], af0, bf);
            mfma(acc[1][0], af1, bf);
        }
        asm volatile("s_nop 7\ns_nop 7\ns_nop 7" : "+a"(acc[0][0]), "+a"(acc[1][0]));
        if (lane < 32) { CNT[lane] = c40; CNT[lane + 32] = c41; }   // in-wave ordered
        int col = l31;
        int D04 = ((const int*)ws)[D4W + col];
        float pb4 = (col < DOUT) ? b4[col] : 0.0f;
        int khr = (lane & 32) >> 3;                  // +4 for hi lanes
#pragma unroll
        for (int f = 0; f < 2; ++f)
#pragma unroll
            for (int rg = 0; rg < 16; ++rg) {
                int rowE = f * 32 + (rg & 3) + 8 * (rg >> 2) + khr;
                int s = (int)CNT[rowE];
                int dotI = D04 - 2 * s + 4 * acc[f][0][rg];
                if (col < DOUT)
                    out[(size_t)(row0 + rowE) * DOUT + col] =
                        __fadd_rn((float)dotI, pb4);
            }
    }
}

extern "C" void kernel_launch(void* const* d_in, const int* in_sizes, int n_in,
                              void* d_out, int out_size, void* d_ws, size_t ws_size,
                              hipStream_t stream)
{
    const float* x   = (const float*)d_in[0];
    const float* w1  = (const float*)d_in[1];
    const float* b1  = (const float*)d_in[2];
    const float* g1  = (const float*)d_in[3];
    const float* be1 = (const float*)d_in[4];
    const float* m1  = (const float*)d_in[5];
    const float* v1  = (const float*)d_in[6];
    const float* w2  = (const float*)d_in[7];
    const float* b2  = (const float*)d_in[8];
    const float* g2  = (const float*)d_in[9];
    const float* be2 = (const float*)d_in[10];
    const float* m2  = (const float*)d_in[11];
    const float* v2  = (const float*)d_in[12];
    const float* w3  = (const float*)d_in[13];
    const float* b3  = (const float*)d_in[14];
    const float* g3  = (const float*)d_in[15];
    const float* be3 = (const float*)d_in[16];
    const float* m3  = (const float*)d_in[17];
    const float* v3  = (const float*)d_in[18];
    const float* w4  = (const float*)d_in[19];
    const float* b4  = (const float*)d_in[20];
    float* out = (float*)d_out;
    u32* ws = (u32*)d_ws;                   // ~1.84 MB used

    const int packWaves = NB + 512 * 13 + 512 * 8 + 512 * 8 + 32 * 8
                        + 512 + 512 + 512 + 32 + 24;
    bmlp_pack<<<dim3((packWaves + 3) / 4), 256, 0, stream>>>(
        x, w1, w2, w3, w4, g1, v1, g2, v2, g3, v3, ws);

    bmlp_bits<<<dim3(NB / 64), THR, 0, stream>>>(
        ws,
        b1, m1, be1,
        b2, m2, be2,
        b3, m3, be3,
        b4, out);
}

// Round 14
// 60.938 us; speedup vs baseline: 1.5040x; 1.0100x over previous
//
#include <hip/hip_runtime.h>
#include <stdint.h>

typedef unsigned int u32;
typedef unsigned long long u64;
typedef int v4i  __attribute__((ext_vector_type(4)));
typedef int v16i __attribute__((ext_vector_type(16)));

// Binarized MLP via i8 MFMA, ±1 bytes, B DIRECT FROM GLOBAL (L2-resident).
// r13 was convoy-bound: 12 weight-staging barriers at 2 waves/SIMD with all
// pipes <40%. r14 deletes the LDS weight path entirely: B-fragments are
// coalesced global_load_dwordx4 from the pre-expanded ±1 i8 layout
// [ks][kh][512col][16] (r10's pack, proven absmax=0); A is bit-packed in
// LDS, expanded in-register to ±1 (nibble-spread, no LUT). Direct dot (no
// cntA/cntB algebra). ~6 barriers total; 50 B-loads pipeline under MFMAs.
// Proven carried verbatim: pack kernel (r10), MFMA asm + s_nop hazards
// (r13), A/B byte<->k pairing (r10), C/D row/col mapping (r13 epilogue).

#define NB    16384
#define DIN   784
#define HID   512
#define DOUT  10
#define MB    64          // rows per block; 256 blocks

// ws byte offsets (r10 layout, verbatim)
#define W1OFF 0           // [25 ks][2 kh][512 col][16] i8  (409600 B)
#define W2OFF 409600      // [16][2][512][16]               (262144 B)
#define W3OFF 671744      // [16][2][512][16]
#define W4OFF 933888      // [16][2][32 col][16], col>=10 zeroed (16384 B)
#define XPOFF 950272      // Xp u32[16384][26]
#define APOFF 2654208     // Apre f32[3][512] = g*(1/sqrt(v+eps)), bit-exact
#define XROW  26

// ---------------- pack: weights->±1 i8, x->bits, BN scale (r10, proven) ---
__global__ void bmlp_pack(const float* __restrict__ x,
                          const float* __restrict__ w1, const float* __restrict__ w2,
                          const float* __restrict__ w3, const float* __restrict__ w4,
                          const float* __restrict__ g1, const float* __restrict__ v1,
                          const float* __restrict__ g2, const float* __restrict__ v2,
                          const float* __restrict__ g3, const float* __restrict__ v3,
                          char* __restrict__ ws)
{
    const int tid = threadIdx.x, lane = tid & 63;
    if (blockIdx.x < 238) {                       // weight/Apre region
        int tt = blockIdx.x * 256 + tid;
        const float* src; int base, K, dst16; bool zero = false;
        if (tt < 25600) {                         // W1
            int r = tt, ks = r >> 10, khh = (r >> 9) & 1, col = r & 511;
            base = ks * 32 + khh * 16; src = w1 + col * DIN; K = DIN; dst16 = r;
        } else if (tt < 41984) {                  // W2
            int r = tt - 25600, ks = r >> 10, khh = (r >> 9) & 1, col = r & 511;
            base = ks * 32 + khh * 16; src = w2 + col * HID; K = HID; dst16 = W2OFF / 16 + r;
        } else if (tt < 58368) {                  // W3
            int r = tt - 41984, ks = r >> 10, khh = (r >> 9) & 1, col = r & 511;
            base = ks * 32 + khh * 16; src = w3 + col * HID; K = HID; dst16 = W3OFF / 16 + r;
        } else if (tt < 59392) {                  // W4 (32-col padded, 10 real)
            int r = tt - 58368, ks = r >> 6, khh = (r >> 5) & 1, col = r & 31;
            base = ks * 32 + khh * 16; src = w4 + col * HID; K = HID; dst16 = W4OFF / 16 + r;
            zero = (col >= DOUT);
        } else {                                  // Apre
            int ai = tt - 59392;
            if (ai < 1536) {
                int ly = ai >> 9, c = ai & 511;
                const float* g = (ly == 0) ? g1 : (ly == 1) ? g2 : g3;
                const float* v = (ly == 0) ? v1 : (ly == 1) ? v2 : v3;
                float eps = (ly == 2) ? 512.0f : 1e-5f;   // EPS3 source bug: 512
                float A = __fmul_rn(g[c], __fdiv_rn(1.0f, __fsqrt_rn(__fadd_rn(v[c], eps))));
                ((float*)(ws + APOFF))[ai] = A;
            }
            return;
        }
        u32 d[4] = {0u, 0u, 0u, 0u};
        if (!zero) {
#pragma unroll
            for (int j = 0; j < 16; ++j) {
                int eg = base + j;
                u32 byte = 0;                     // K-pad -> 0 (kills act-pad garbage)
                if (eg < K) byte = (src[eg] < 0.0f) ? 0xFFu : 0x01u;   // -1 / +1
                d[j >> 2] |= byte << ((j & 3) * 8);
            }
        }
        v4i val; val.x = (int)d[0]; val.y = (int)d[1]; val.z = (int)d[2]; val.w = (int)d[3];
        ((v4i*)ws)[dst16] = val;
    } else {                                      // x bit-pack
        int wvi = (blockIdx.x - 238) * 4 + (tid >> 6);
        if (wvi >= NB * 13) return;
        int row = wvi / 13, j = wvi - row * 13;
        int e = j * 64 + lane;
        float v = (e < DIN) ? x[row * DIN + e] : 1.0f;    // pad bits 0
        u64 bal = __ballot(v < 0.0f);
        if (lane == 0) *(u64*)(ws + XPOFF + row * 104 + j * 8) = bal;
    }
}

// ---------------- fused MLP ----------------
// 16 bits -> 16 ±1 bytes: spread bit b to byte, pm = 1 + 254*b (1 / 0xFF).
__device__ __forceinline__ v4i expandpm(u32 sel)
{
    u32 e0 = (((sel      ) & 15u) * 0x00204081u) & 0x01010101u;
    u32 e1 = (((sel >> 4 ) & 15u) * 0x00204081u) & 0x01010101u;
    u32 e2 = (((sel >> 8 ) & 15u) * 0x00204081u) & 0x01010101u;
    u32 e3 = (((sel >> 12) & 15u) * 0x00204081u) & 0x01010101u;
    v4i r;
    r.x = (int)(0x01010101u + e0 * 254u);
    r.y = (int)(0x01010101u + e1 * 254u);
    r.z = (int)(0x01010101u + e2 * 254u);
    r.w = (int)(0x01010101u + e3 * 254u);
    return r;
}

// s_nop 2 covers VALU-write -> MFMA-read-SrcA/B wait states the compiler
// cannot insert around opaque inline asm (r12 lesson; r13 proven).
__device__ __forceinline__ void mfma(v16i& a, v4i af, v4i bf)
{
    asm("s_nop 2\n\tv_mfma_i32_32x32x32_i8 %0, %1, %2, %0"
        : "+a"(a) : "v"(af), "v"(bf));
}

// K-loop: A bits from LDS (broadcast b32, odd stride), B ±1 bytes direct
// from global (coalesced b128, L2-hot). No barriers inside.
template<int NK, int ASTR>
__device__ __forceinline__ void kloopg(const char* __restrict__ Wg,
                                       const u32* a0p, const u32* a1p,
                                       int kh16, int coloff, v16i acc[2][2])
{
#pragma unroll
    for (int ks = 0; ks < NK; ++ks) {
        u32 aw0 = a0p[ks], aw1 = a1p[ks];
        v4i af0 = expandpm((aw0 >> kh16) & 0xFFFFu);
        v4i af1 = expandpm((aw1 >> kh16) & 0xFFFFu);
        const v4i* br = (const v4i*)Wg + (size_t)(2 * ks + (kh16 >> 4)) * 512 + coloff;
        v4i bf0 = br[0], bf1 = br[32];
        mfma(acc[0][0], af0, bf0); mfma(acc[0][1], af0, bf1);
        mfma(acc[1][0], af1, bf0); mfma(acc[1][1], af1, bf1);
    }
}

// BN + sign -> ballot -> bit-packed acts. Exact reference op order
// (r13-proven): xl = dot + b; y = ((xl - m)*A) + be; dot = acc directly.
// C/D row for THIS lane = f*32 + (rg&3)+8*(rg>>2) + 4*(lane>>5).
__device__ __forceinline__ void epilogue(v16i acc[2][2], u32* dst,
    const float* __restrict__ b, const float* __restrict__ m,
    const float* __restrict__ be, const float* __restrict__ Ap,
    int lane, int wv)
{
    asm volatile("s_nop 7\ns_nop 7\ns_nop 7"        // MFMA->read fence
        : "+a"(acc[0][0]), "+a"(acc[0][1]), "+a"(acc[1][0]), "+a"(acc[1][1]));
    const int l31 = lane & 31;
    const int rAdd = (lane & 32) >> 3;              // +4 for hi lanes
    float pb[2], pm[2], pe[2], pA[2];
#pragma unroll
    for (int c = 0; c < 2; ++c) {
        int col = wv * 64 + c * 32 + l31;
        pb[c] = b[col]; pm[c] = m[col]; pe[c] = be[col]; pA[c] = Ap[col];
    }
#pragma unroll
    for (int f = 0; f < 2; ++f)
#pragma unroll
        for (int rg = 0; rg < 16; ++rg) {
            int rowMe = f * 32 + (rg & 3) + 8 * (rg >> 2) + rAdd;
#pragma unroll
            for (int c = 0; c < 2; ++c) {
                float xl = __fadd_rn((float)acc[f][c][rg], pb[c]);
                float y  = __fadd_rn(__fmul_rn(__fsub_rn(xl, pm[c]), pA[c]), pe[c]);
                u64 bal = __ballot(y < 0.0f);       // bit=1 <=> -1
                if (!(lane & 31))                   // lanes 0 and 32
                    dst[rowMe * 17 + (wv * 2 + c)] = (u32)(bal >> ((lane >> 5) << 5));
                acc[f][c][rg] = 0;
            }
        }
}

__global__ __launch_bounds__(512)
void bmlp_direct(const char* __restrict__ ws,
                 const float* __restrict__ b1, const float* __restrict__ m1, const float* __restrict__ be1,
                 const float* __restrict__ b2, const float* __restrict__ m2, const float* __restrict__ be2,
                 const float* __restrict__ b3, const float* __restrict__ m3, const float* __restrict__ be3,
                 const float* __restrict__ b4, float* __restrict__ out)
{
    __shared__ u32 A1s[64 * 27];        // L1 act bits, odd stride 27
    __shared__ u32 AA[64 * 17];         // L1/L3 out acts, odd stride 17
    __shared__ u32 AB[64 * 17];         // L2 out acts

    const int tid = threadIdx.x, lane = tid & 63, wv = tid >> 6;
    const int l31 = lane & 31;
    const int kh16 = (lane & 32) >> 1;              // 0 / 16
    const int row0 = blockIdx.x * MB;
    const int coloff = wv * 64 + l31;               // v4i index within k-slice

    const u32* Xpg = (const u32*)(ws + XPOFF);
    const float* Ap = (const float*)(ws + APOFF);

    // stage act bits (64 rows x 26 words), coalesced
    for (int i = tid; i < 64 * 26; i += 512) {
        int r = i / 26, wd = i - r * 26;
        A1s[r * 27 + wd] = Xpg[(size_t)(row0 + r) * 26 + wd];
    }
    __syncthreads();

    v16i acc[2][2];
#pragma unroll
    for (int f = 0; f < 2; ++f)
#pragma unroll
        for (int c = 0; c < 2; ++c)
#pragma unroll
            for (int i = 0; i < 16; ++i) acc[f][c][i] = 0;

    // ---- L1 (25 k-slices; weight pads are 0 -> act pad bits harmless) ----
    kloopg<25, 27>(ws + W1OFF, A1s + l31 * 27, A1s + (l31 + 32) * 27, kh16, coloff, acc);
    epilogue(acc, AA, b1, m1, be1, Ap, lane, wv);
    __syncthreads();

    // ---- L2 (16 slices) ----
    kloopg<16, 17>(ws + W2OFF, AA + l31 * 17, AA + (l31 + 32) * 17, kh16, coloff, acc);
    epilogue(acc, AB, b2, m2, be2, Ap + 512, lane, wv);
    __syncthreads();

    // ---- L3 (eps=512 folded into Apre) ----
    kloopg<16, 17>(ws + W3OFF, AB + l31 * 17, AB + (l31 + 32) * 17, kh16, coloff, acc);
    epilogue(acc, AA, b3, m3, be3, Ap + 1024, lane, wv);
    __syncthreads();                                 // AA complete before L4

    // ---- L4: wave 0 only; out = dot + b4 ----
    if (wv == 0) {
        const int kh = kh16 >> 4;
#pragma unroll
        for (int ks = 0; ks < 16; ++ks) {
            u32 aw0 = AA[l31 * 17 + ks], aw1 = AA[(l31 + 32) * 17 + ks];
            v4i af0 = expandpm((aw0 >> kh16) & 0xFFFFu);
            v4i af1 = expandpm((aw1 >> kh16) & 0xFFFFu);
            v4i bf = *(const v4i*)(ws + W4OFF + (size_t)(((ks * 2 + kh) * 32) + l31) * 16);
            mfma(acc[0][0], af0, bf);
            mfma(acc[1][0], af1, bf);
        }
        asm volatile("s_nop 7\ns_nop 7\ns_nop 7" : "+a"(acc[0][0]), "+a"(acc[1][0]));
        int col = l31;
        int rAdd = (lane & 32) >> 3;
        if (col < DOUT) {
            float pb4 = b4[col];
#pragma unroll
            for (int f = 0; f < 2; ++f)
#pragma unroll
                for (int rg = 0; rg < 16; ++rg) {
                    int rowE = f * 32 + (rg & 3) + 8 * (rg >> 2) + rAdd;
                    out[(size_t)(row0 + rowE) * DOUT + col] =
                        __fadd_rn((float)acc[f][0][rg], pb4);
                }
        }
    }
}

extern "C" void kernel_launch(void* const* d_in, const int* in_sizes, int n_in,
                              void* d_out, int out_size, void* d_ws, size_t ws_size,
                              hipStream_t stream)
{
    const float* x   = (const float*)d_in[0];
    const float* w1  = (const float*)d_in[1];
    const float* b1  = (const float*)d_in[2];
    const float* g1  = (const float*)d_in[3];
    const float* be1 = (const float*)d_in[4];
    const float* m1  = (const float*)d_in[5];
    const float* v1  = (const float*)d_in[6];
    const float* w2  = (const float*)d_in[7];
    const float* b2  = (const float*)d_in[8];
    const float* g2  = (const float*)d_in[9];
    const float* be2 = (const float*)d_in[10];
    const float* m2  = (const float*)d_in[11];
    const float* v2  = (const float*)d_in[12];
    const float* w3  = (const float*)d_in[13];
    const float* b3  = (const float*)d_in[14];
    const float* g3  = (const float*)d_in[15];
    const float* be3 = (const float*)d_in[16];
    const float* m3  = (const float*)d_in[17];
    const float* v3  = (const float*)d_in[18];
    const float* w4  = (const float*)d_in[19];
    const float* b4  = (const float*)d_in[20];
    float* out = (float*)d_out;
    char* ws = (char*)d_ws;                 // ~2.66 MB used

    bmlp_pack<<<dim3(238 + NB * 13 / 4), 256, 0, stream>>>(
        x, w1, w2, w3, w4, g1, v1, g2, v2, g3, v3, ws);

    bmlp_direct<<<dim3(NB / MB), 512, 0, stream>>>(
        ws,
        b1, m1, be1,
        b2, m2, be2,
        b3, m3, be3,
        b4, out);
}

// Round 15
// 52.408 us; speedup vs baseline: 1.7488x; 1.1628x over previous
//
#include <hip/hip_runtime.h>
#include <stdint.h>

typedef unsigned int u32;
typedef unsigned long long u64;
typedef int v4i  __attribute__((ext_vector_type(4)));
typedef int v16i __attribute__((ext_vector_type(16)));

// Binarized MLP via i8 MFMA, ±1 bytes, B direct from global (L2-resident).
// r15 = r14 dataflow (proven absmax=0) with 2x TLP:
//  - 1024-thr blocks (16 waves, MB=64, grid 256) -> 4 waves/SIMD (was 2).
//    Wave owns a 32-col slice (col = wv*32+l31): 1 B-frag x 2 row-frags,
//    acc = 32 AGPRs (was 64) -> register headroom for B-load pipelining.
//    L2 weight traffic unchanged (each block reads weights exactly once).
//  - x-pack inlined (r8-proven: wave packs 4 rows, 13-wide ILP, ballot->LDS);
//    pack dispatch now weights+Apre only (~2us).
// Verbatim-proven pieces: weight pack layout (r10), MFMA asm + s_nop hazard
// (r13), expandpm (r14), C/D row mapping + ballot act-repack (r13/r14),
// exact BN op order, bit-exact Apre.

#define NB    16384
#define DIN   784
#define HID   512
#define DOUT  10
#define MB    64          // rows per block; 256 blocks

// ws byte offsets (r10 layout)
#define W1OFF 0           // [25 ks][2 kh][512 col][16] i8  (409600 B)
#define W2OFF 409600      // [16][2][512][16]               (262144 B)
#define W3OFF 671744      // [16][2][512][16]
#define W4OFF 933888      // [16][2][32 col][16], col>=10 zeroed (16384 B)
#define APOFF 950272      // Apre f32[3][512] = g*(1/sqrt(v+eps)), bit-exact

// ---------------- pack: weights->±1 i8 + Apre (r10 logic, x branch removed)
__global__ void bmlp_pack(const float* __restrict__ w1, const float* __restrict__ w2,
                          const float* __restrict__ w3, const float* __restrict__ w4,
                          const float* __restrict__ g1, const float* __restrict__ v1,
                          const float* __restrict__ g2, const float* __restrict__ v2,
                          const float* __restrict__ g3, const float* __restrict__ v3,
                          char* __restrict__ ws)
{
    int tt = blockIdx.x * 256 + (int)threadIdx.x;
    const float* src; int base, K, dst16; bool zero = false;
    if (tt < 25600) {                         // W1
        int r = tt, ks = r >> 10, khh = (r >> 9) & 1, col = r & 511;
        base = ks * 32 + khh * 16; src = w1 + col * DIN; K = DIN; dst16 = r;
    } else if (tt < 41984) {                  // W2
        int r = tt - 25600, ks = r >> 10, khh = (r >> 9) & 1, col = r & 511;
        base = ks * 32 + khh * 16; src = w2 + col * HID; K = HID; dst16 = W2OFF / 16 + r;
    } else if (tt < 58368) {                  // W3
        int r = tt - 41984, ks = r >> 10, khh = (r >> 9) & 1, col = r & 511;
        base = ks * 32 + khh * 16; src = w3 + col * HID; K = HID; dst16 = W3OFF / 16 + r;
    } else if (tt < 59392) {                  // W4 (32-col padded, 10 real)
        int r = tt - 58368, ks = r >> 6, khh = (r >> 5) & 1, col = r & 31;
        base = ks * 32 + khh * 16; src = w4 + col * HID; K = HID; dst16 = W4OFF / 16 + r;
        zero = (col >= DOUT);
    } else {                                  // Apre
        int ai = tt - 59392;
        if (ai < 1536) {
            int ly = ai >> 9, c = ai & 511;
            const float* g = (ly == 0) ? g1 : (ly == 1) ? g2 : g3;
            const float* v = (ly == 0) ? v1 : (ly == 1) ? v2 : v3;
            float eps = (ly == 2) ? 512.0f : 1e-5f;   // EPS3 source bug: 512
            float A = __fmul_rn(g[c], __fdiv_rn(1.0f, __fsqrt_rn(__fadd_rn(v[c], eps))));
            ((float*)(ws + APOFF))[ai] = A;
        }
        return;
    }
    u32 d[4] = {0u, 0u, 0u, 0u};
    if (!zero) {
#pragma unroll
        for (int j = 0; j < 16; ++j) {
            int eg = base + j;
            u32 byte = 0;                     // K-pad -> 0 (kills act-pad garbage)
            if (eg < K) byte = (src[eg] < 0.0f) ? 0xFFu : 0x01u;   // -1 / +1
            d[j >> 2] |= byte << ((j & 3) * 8);
        }
    }
    v4i val; val.x = (int)d[0]; val.y = (int)d[1]; val.z = (int)d[2]; val.w = (int)d[3];
    ((v4i*)ws)[dst16] = val;
}

// ---------------- fused MLP ----------------
// 16 bits -> 16 ±1 bytes: spread bit to byte, 1 + 254*b (0x01 / 0xFF).
__device__ __forceinline__ v4i expandpm(u32 sel)
{
    u32 e0 = (((sel      ) & 15u) * 0x00204081u) & 0x01010101u;
    u32 e1 = (((sel >> 4 ) & 15u) * 0x00204081u) & 0x01010101u;
    u32 e2 = (((sel >> 8 ) & 15u) * 0x00204081u) & 0x01010101u;
    u32 e3 = (((sel >> 12) & 15u) * 0x00204081u) & 0x01010101u;
    v4i r;
    r.x = (int)(0x01010101u + e0 * 254u);
    r.y = (int)(0x01010101u + e1 * 254u);
    r.z = (int)(0x01010101u + e2 * 254u);
    r.w = (int)(0x01010101u + e3 * 254u);
    return r;
}

// s_nop 2 covers VALU-write -> MFMA-read-SrcA/B wait states the compiler
// cannot insert around opaque inline asm (r12 lesson; r13/r14 proven).
__device__ __forceinline__ void mfma(v16i& a, v4i af, v4i bf)
{
    asm("s_nop 2\n\tv_mfma_i32_32x32x32_i8 %0, %1, %2, %0"
        : "+a"(a) : "v"(af), "v"(bf));
}

// K-loop: A bits from LDS (broadcast b32, odd stride), B ±1 bytes direct
// from global (coalesced b128, L2-hot). 1 B-frag x 2 row-frags per wave.
template<int NK>
__device__ __forceinline__ void kloopg(const char* __restrict__ Wg,
                                       const u32* a0p, const u32* a1p,
                                       int kh16, int col, v16i acc[2])
{
#pragma unroll
    for (int ks = 0; ks < NK; ++ks) {
        u32 aw0 = a0p[ks], aw1 = a1p[ks];
        v4i af0 = expandpm((aw0 >> kh16) & 0xFFFFu);
        v4i af1 = expandpm((aw1 >> kh16) & 0xFFFFu);
        v4i bf = ((const v4i*)Wg)[(size_t)(2 * ks + (kh16 >> 4)) * 512 + col];
        mfma(acc[0], af0, bf);
        mfma(acc[1], af1, bf);
    }
}

// BN + sign -> ballot -> bit-packed acts (r13/r14-proven, single col-frag).
// C/D row for THIS lane = f*32 + (rg&3)+8*(rg>>2) + 4*(lane>>5).
__device__ __forceinline__ void epilogue(v16i acc[2], u32* dst,
    const float* __restrict__ b, const float* __restrict__ m,
    const float* __restrict__ be, const float* __restrict__ Ap,
    int lane, int wv)
{
    asm volatile("s_nop 7\ns_nop 7\ns_nop 7"        // MFMA->read fence
        : "+a"(acc[0]), "+a"(acc[1]));
    const int l31 = lane & 31;
    const int rAdd = (lane & 32) >> 3;              // +4 for hi lanes
    const int col = wv * 32 + l31;
    const float pb = b[col], pm = m[col], pe = be[col], pA = Ap[col];
#pragma unroll
    for (int f = 0; f < 2; ++f)
#pragma unroll
        for (int rg = 0; rg < 16; ++rg) {
            int rowMe = f * 32 + (rg & 3) + 8 * (rg >> 2) + rAdd;
            float xl = __fadd_rn((float)acc[f][rg], pb);
            float y  = __fadd_rn(__fmul_rn(__fsub_rn(xl, pm), pA), pe);
            u64 bal = __ballot(y < 0.0f);           // bit=1 <=> -1
            if (!(lane & 31))                       // lanes 0 and 32
                dst[rowMe * 17 + wv] = (u32)(bal >> ((lane >> 5) << 5));
            acc[f][rg] = 0;
        }
}

__global__ __launch_bounds__(1024, 2)
void bmlp_direct(const float* __restrict__ x, const char* __restrict__ ws,
                 const float* __restrict__ b1, const float* __restrict__ m1, const float* __restrict__ be1,
                 const float* __restrict__ b2, const float* __restrict__ m2, const float* __restrict__ be2,
                 const float* __restrict__ b3, const float* __restrict__ m3, const float* __restrict__ be3,
                 const float* __restrict__ b4, float* __restrict__ out)
{
    __shared__ u32 A1s[64 * 27];        // L1 act bits, odd stride 27
    __shared__ u32 AA[64 * 17];         // L1/L3 out acts, odd stride 17
    __shared__ u32 AB[64 * 17];         // L2 out acts

    const int tid = threadIdx.x, lane = tid & 63, wv = tid >> 6;   // wv 0..15
    const int l31 = lane & 31;
    const int kh16 = (lane & 32) >> 1;              // 0 / 16
    const int row0 = blockIdx.x * MB;
    const int col = wv * 32 + l31;                  // this wave's B column

    const float* Ap = (const float*)(ws + APOFF);

    // inline x-pack: wave wv packs rows [4wv, 4wv+4) (13-wide ILP, r8-proven)
#pragma unroll 1
    for (int r = 0; r < 4; ++r) {
        const int row = wv * 4 + r;
        const float* xr = x + (size_t)(row0 + row) * DIN;
        float vx[13];
#pragma unroll
        for (int k = 0; k < 13; ++k) {
            int e = k * 64 + lane;
            vx[k] = (e < DIN) ? xr[e] : 1.0f;       // pad -> bit 0
        }
#pragma unroll
        for (int k = 0; k < 13; ++k) {
            u64 bal = __ballot(vx[k] < 0.0f);
            if (lane == 0) {
                A1s[row * 27 + 2 * k]     = (u32)bal;
                A1s[row * 27 + 2 * k + 1] = (u32)(bal >> 32);
            }
        }
    }
    __syncthreads();

    v16i acc[2];
#pragma unroll
    for (int f = 0; f < 2; ++f)
#pragma unroll
        for (int i = 0; i < 16; ++i) acc[f][i] = 0;

    // ---- L1 (25 k-slices; weight pads are 0 -> act pad bits harmless) ----
    kloopg<25>(ws + W1OFF, A1s + l31 * 27, A1s + (l31 + 32) * 27, kh16, col, acc);
    epilogue(acc, AA, b1, m1, be1, Ap, lane, wv);
    __syncthreads();

    // ---- L2 (16 slices) ----
    kloopg<16>(ws + W2OFF, AA + l31 * 17, AA + (l31 + 32) * 17, kh16, col, acc);
    epilogue(acc, AB, b2, m2, be2, Ap + 512, lane, wv);
    __syncthreads();

    // ---- L3 (eps=512 folded into Apre) ----
    kloopg<16>(ws + W3OFF, AB + l31 * 17, AB + (l31 + 32) * 17, kh16, col, acc);
    epilogue(acc, AA, b3, m3, be3, Ap + 1024, lane, wv);
    __syncthreads();                                 // AA complete before L4

    // ---- L4: wave 0 only; out = dot + b4 ----
    if (wv == 0) {
        const int kh = kh16 >> 4;
#pragma unroll
        for (int ks = 0; ks < 16; ++ks) {
            u32 aw0 = AA[l31 * 17 + ks], aw1 = AA[(l31 + 32) * 17 + ks];
            v4i af0 = expandpm((aw0 >> kh16) & 0xFFFFu);
            v4i af1 = expandpm((aw1 >> kh16) & 0xFFFFu);
            v4i bf = *(const v4i*)(ws + W4OFF + (size_t)((ks * 2 + kh) * 32 + l31) * 16);
            mfma(acc[0], af0, bf);
            mfma(acc[1], af1, bf);
        }
        asm volatile("s_nop 7\ns_nop 7\ns_nop 7" : "+a"(acc[0]), "+a"(acc[1]));
        const int rAdd = (lane & 32) >> 3;
        if (l31 < DOUT) {
            float pb4 = b4[l31];
#pragma unroll
            for (int f = 0; f < 2; ++f)
#pragma unroll
                for (int rg = 0; rg < 16; ++rg) {
                    int rowE = f * 32 + (rg & 3) + 8 * (rg >> 2) + rAdd;
                    out[(size_t)(row0 + rowE) * DOUT + l31] =
                        __fadd_rn((float)acc[f][rg], pb4);
                }
        }
    }
}

extern "C" void kernel_launch(void* const* d_in, const int* in_sizes, int n_in,
                              void* d_out, int out_size, void* d_ws, size_t ws_size,
                              hipStream_t stream)
{
    const float* x   = (const float*)d_in[0];
    const float* w1  = (const float*)d_in[1];
    const float* b1  = (const float*)d_in[2];
    const float* g1  = (const float*)d_in[3];
    const float* be1 = (const float*)d_in[4];
    const float* m1  = (const float*)d_in[5];
    const float* v1  = (const float*)d_in[6];
    const float* w2  = (const float*)d_in[7];
    const float* b2  = (const float*)d_in[8];
    const float* g2  = (const float*)d_in[9];
    const float* be2 = (const float*)d_in[10];
    const float* m2  = (const float*)d_in[11];
    const float* v2  = (const float*)d_in[12];
    const float* w3  = (const float*)d_in[13];
    const float* b3  = (const float*)d_in[14];
    const float* g3  = (const float*)d_in[15];
    const float* be3 = (const float*)d_in[16];
    const float* m3  = (const float*)d_in[17];
    const float* v3  = (const float*)d_in[18];
    const float* w4  = (const float*)d_in[19];
    const float* b4  = (const float*)d_in[20];
    float* out = (float*)d_out;
    char* ws = (char*)d_ws;                 // ~956 KB used

    // weights + Apre only: 59392+1536 threads -> 238 blocks of 256
    bmlp_pack<<<dim3(238), 256, 0, stream>>>(
        w1, w2, w3, w4, g1, v1, g2, v2, g3, v3, ws);

    bmlp_direct<<<dim3(NB / MB), 1024, 0, stream>>>(
        x, ws,
        b1, m1, be1,
        b2, m2, be2,
        b3, m3, be3,
        b4, out);
}

// Round 16
// 41.058 us; speedup vs baseline: 2.2322x; 1.2764x over previous
//
#include <hip/hip_runtime.h>
#include <stdint.h>

typedef unsigned int u32;
typedef unsigned long long u64;
typedef int v4i  __attribute__((ext_vector_type(4)));
typedef int v16i __attribute__((ext_vector_type(16)));

// Binarized MLP via i8 MFMA, ±1 bytes, B direct from global (L2-resident).
// r16 = r15 minus the 16x-redundant in-loop A expand: acts are expanded
// ONCE per block, cooperatively, into a swizzled LDS i8 buffer Ai8[64][512]
// (slot ^= row&7 -> conflict-free ds_read_b128 across rows; guide T2/G4).
// K-loop is now 2 ds_read_b128 + 1 global b128 + 2 MFMA + addr per step.
// L1 (800B/row) streams through Ai8 in two k-chunks. Verbatim-proven: pack
// (r10/r15), MFMA asm + s_nop2 hazard (r13), expandpm (r14), epilogue C/D
// map + ballot repack (r13-15), exact BN order, bit-exact Apre, L4 (r15).

#define NB    16384
#define DIN   784
#define HID   512
#define DOUT  10
#define MB    64          // rows per block; 256 blocks

// ws byte offsets (r10 layout)
#define W1OFF 0           // [25 ks][2 kh][512 col][16] i8  (409600 B)
#define W2OFF 409600      // [16][2][512][16]               (262144 B)
#define W3OFF 671744      // [16][2][512][16]
#define W4OFF 933888      // [16][2][32 col][16], col>=10 zeroed (16384 B)
#define APOFF 950272      // Apre f32[3][512] = g*(1/sqrt(v+eps)), bit-exact

// ---------------- pack: weights->±1 i8 + Apre (r15 verbatim) ----------------
__global__ void bmlp_pack(const float* __restrict__ w1, const float* __restrict__ w2,
                          const float* __restrict__ w3, const float* __restrict__ w4,
                          const float* __restrict__ g1, const float* __restrict__ v1,
                          const float* __restrict__ g2, const float* __restrict__ v2,
                          const float* __restrict__ g3, const float* __restrict__ v3,
                          char* __restrict__ ws)
{
    int tt = blockIdx.x * 256 + (int)threadIdx.x;
    const float* src; int base, K, dst16; bool zero = false;
    if (tt < 25600) {                         // W1
        int r = tt, ks = r >> 10, khh = (r >> 9) & 1, col = r & 511;
        base = ks * 32 + khh * 16; src = w1 + col * DIN; K = DIN; dst16 = r;
    } else if (tt < 41984) {                  // W2
        int r = tt - 25600, ks = r >> 10, khh = (r >> 9) & 1, col = r & 511;
        base = ks * 32 + khh * 16; src = w2 + col * HID; K = HID; dst16 = W2OFF / 16 + r;
    } else if (tt < 58368) {                  // W3
        int r = tt - 41984, ks = r >> 10, khh = (r >> 9) & 1, col = r & 511;
        base = ks * 32 + khh * 16; src = w3 + col * HID; K = HID; dst16 = W3OFF / 16 + r;
    } else if (tt < 59392) {                  // W4 (32-col padded, 10 real)
        int r = tt - 58368, ks = r >> 6, khh = (r >> 5) & 1, col = r & 31;
        base = ks * 32 + khh * 16; src = w4 + col * HID; K = HID; dst16 = W4OFF / 16 + r;
        zero = (col >= DOUT);
    } else {                                  // Apre
        int ai = tt - 59392;
        if (ai < 1536) {
            int ly = ai >> 9, c = ai & 511;
            const float* g = (ly == 0) ? g1 : (ly == 1) ? g2 : g3;
            const float* v = (ly == 0) ? v1 : (ly == 1) ? v2 : v3;
            float eps = (ly == 2) ? 512.0f : 1e-5f;   // EPS3 source bug: 512
            float A = __fmul_rn(g[c], __fdiv_rn(1.0f, __fsqrt_rn(__fadd_rn(v[c], eps))));
            ((float*)(ws + APOFF))[ai] = A;
        }
        return;
    }
    u32 d[4] = {0u, 0u, 0u, 0u};
    if (!zero) {
#pragma unroll
        for (int j = 0; j < 16; ++j) {
            int eg = base + j;
            u32 byte = 0;                     // K-pad -> 0 (kills act-pad +1 bytes)
            if (eg < K) byte = (src[eg] < 0.0f) ? 0xFFu : 0x01u;   // -1 / +1
            d[j >> 2] |= byte << ((j & 3) * 8);
        }
    }
    v4i val; val.x = (int)d[0]; val.y = (int)d[1]; val.z = (int)d[2]; val.w = (int)d[3];
    ((v4i*)ws)[dst16] = val;
}

// ---------------- fused MLP ----------------
// 16 bits -> 16 ±1 bytes (bit j -> byte j): 0x01 / 0xFF. (r14-proven)
__device__ __forceinline__ v4i expandpm(u32 sel)
{
    u32 e0 = (((sel      ) & 15u) * 0x00204081u) & 0x01010101u;
    u32 e1 = (((sel >> 4 ) & 15u) * 0x00204081u) & 0x01010101u;
    u32 e2 = (((sel >> 8 ) & 15u) * 0x00204081u) & 0x01010101u;
    u32 e3 = (((sel >> 12) & 15u) * 0x00204081u) & 0x01010101u;
    v4i r;
    r.x = (int)(0x01010101u + e0 * 254u);
    r.y = (int)(0x01010101u + e1 * 254u);
    r.z = (int)(0x01010101u + e2 * 254u);
    r.w = (int)(0x01010101u + e3 * 254u);
    return r;
}

// s_nop 2 covers VALU-write -> MFMA-read wait states around opaque inline
// asm (r12 lesson; r13-r15 proven). Needed for acc-rezero and L4 paths.
__device__ __forceinline__ void mfma(v16i& a, v4i af, v4i bf)
{
    asm("s_nop 2\n\tv_mfma_i32_32x32x32_i8 %0, %1, %2, %0"
        : "+a"(a) : "v"(af), "v"(bf));
}

// Expand one act bit-word (row, bits [32w,32w+32)) into Ai8 slots 2w,2w+1
// with XOR swizzle slot ^= row&7 (within 128B stripes; stride 512 = 4x128).
__device__ __forceinline__ void expand_to(char* Ai8, int row, int slotBase, u32 aw)
{
    int r7 = row & 7;
    v4i lo = expandpm(aw & 0xFFFFu);
    v4i hi = expandpm(aw >> 16);
    *(v4i*)(Ai8 + row * 512 + ((slotBase    ) ^ r7) * 16) = lo;
    *(v4i*)(Ai8 + row * 512 + ((slotBase + 1) ^ r7) * 16) = hi;
}

// K-loop: A ±1 bytes from swizzled LDS (2x ds_read_b128, conflict-free),
// B ±1 bytes direct from global (coalesced b128, L2-hot). 2 MFMA/step.
template<int NK>
__device__ __forceinline__ void kloopL(const char* A, const char* __restrict__ Wg,
                                       int kh, int sxor, int arow, int col,
                                       v16i acc[2])
{
#pragma unroll
    for (int ks = 0; ks < NK; ++ks) {
        int s = 2 * ks + kh;
        int soff = ((s ^ sxor) << 4);
        v4i af0 = *(const v4i*)(A + arow + soff);            // row l31
        v4i af1 = *(const v4i*)(A + arow + 16384 + soff);    // row l31+32
        v4i bf = ((const v4i*)Wg)[(size_t)s * 512 + col];
        mfma(acc[0], af0, bf);
        mfma(acc[1], af1, bf);
    }
}

// BN + sign -> ballot -> bit-packed acts (r13-r15 proven, verbatim).
__device__ __forceinline__ void epilogue(v16i acc[2], u32* dst,
    const float* __restrict__ b, const float* __restrict__ m,
    const float* __restrict__ be, const float* __restrict__ Ap,
    int lane, int wv)
{
    asm volatile("s_nop 7\ns_nop 7\ns_nop 7"        // MFMA->read fence
        : "+a"(acc[0]), "+a"(acc[1]));
    const int l31 = lane & 31;
    const int rAdd = (lane & 32) >> 3;              // +4 for hi lanes
    const int col = wv * 32 + l31;
    const float pb = b[col], pm = m[col], pe = be[col], pA = Ap[col];
#pragma unroll
    for (int f = 0; f < 2; ++f)
#pragma unroll
        for (int rg = 0; rg < 16; ++rg) {
            int rowMe = f * 32 + (rg & 3) + 8 * (rg >> 2) + rAdd;
            float xl = __fadd_rn((float)acc[f][rg], pb);
            float y  = __fadd_rn(__fmul_rn(__fsub_rn(xl, pm), pA), pe);
            u64 bal = __ballot(y < 0.0f);           // bit=1 <=> -1
            if (!(lane & 31))                       // lanes 0 and 32
                dst[rowMe * 17 + wv] = (u32)(bal >> ((lane >> 5) << 5));
            acc[f][rg] = 0;
        }
}

__global__ __launch_bounds__(1024, 2)
void bmlp_direct(const float* __restrict__ x, const char* __restrict__ ws,
                 const float* __restrict__ b1, const float* __restrict__ m1, const float* __restrict__ be1,
                 const float* __restrict__ b2, const float* __restrict__ m2, const float* __restrict__ be2,
                 const float* __restrict__ b3, const float* __restrict__ m3, const float* __restrict__ be3,
                 const float* __restrict__ b4, float* __restrict__ out)
{
    __shared__ __align__(16) char Ai8[64 * 512];    // ±1 act bytes, swizzled (32 KB)
    __shared__ u32 A1s[64 * 26];        // L1 act bits
    __shared__ u32 AA[64 * 17];         // L1/L3 out act bits
    __shared__ u32 AB[64 * 17];         // L2 out act bits

    const int tid = threadIdx.x, lane = tid & 63, wv = tid >> 6;   // wv 0..15
    const int l31 = lane & 31;
    const int kh16 = (lane & 32) >> 1;              // 0 / 16
    const int kh = kh16 >> 4;                       // 0 / 1
    const int sxor = l31 & 7;                       // read-side swizzle
    const int arow = l31 * 512;                     // row base in Ai8
    const int row0 = blockIdx.x * MB;
    const int col = wv * 32 + l31;                  // this wave's B column

    const float* Ap = (const float*)(ws + APOFF);

    // inline x-pack: wave wv packs rows [4wv,4wv+4) (13-wide ILP, r15-proven)
#pragma unroll 1
    for (int r = 0; r < 4; ++r) {
        const int row = wv * 4 + r;
        const float* xr = x + (size_t)(row0 + row) * DIN;
        float vx[13];
#pragma unroll
        for (int k = 0; k < 13; ++k) {
            int e = k * 64 + lane;
            vx[k] = (e < DIN) ? xr[e] : 1.0f;       // pad -> bit 0
        }
#pragma unroll
        for (int k = 0; k < 13; ++k) {
            u64 bal = __ballot(vx[k] < 0.0f);
            if (lane == 0) {
                A1s[row * 26 + 2 * k]     = (u32)bal;
                A1s[row * 26 + 2 * k + 1] = (u32)(bal >> 32);
            }
        }
    }
    __syncthreads();

    v16i acc[2];
#pragma unroll
    for (int f = 0; f < 2; ++f)
#pragma unroll
        for (int i = 0; i < 16; ++i) acc[f][i] = 0;

    // ---- L1 chunk A: k-words 0..12 (ks 0..12) ----
    if (tid < 832) {
        int row = tid / 13, w = tid - row * 13;
        expand_to(Ai8, row, 2 * w, A1s[row * 26 + w]);
    }
    __syncthreads();
    kloopL<13>(Ai8, ws + W1OFF, kh, sxor, arow, col, acc);
    __syncthreads();
    // ---- L1 chunk B: k-words 13..24 (ks 13..24; word 24 has zero pads,
    //      matching zero weight-pad bytes) ----
    if (tid < 768) {
        int row = tid / 12, w = tid - row * 12;
        expand_to(Ai8, row, 2 * w, A1s[row * 26 + 13 + w]);
    }
    __syncthreads();
    kloopL<12>(Ai8, ws + W1OFF + 13 * 16384, kh, sxor, arow, col, acc);
    epilogue(acc, AA, b1, m1, be1, Ap, lane, wv);
    __syncthreads();

    // ---- L2 ----
    { int row = tid >> 4, w = tid & 15; expand_to(Ai8, row, 2 * w, AA[row * 17 + w]); }
    __syncthreads();
    kloopL<16>(Ai8, ws + W2OFF, kh, sxor, arow, col, acc);
    epilogue(acc, AB, b2, m2, be2, Ap + 512, lane, wv);
    __syncthreads();

    // ---- L3 (eps=512 folded into Apre) ----
    { int row = tid >> 4, w = tid & 15; expand_to(Ai8, row, 2 * w, AB[row * 17 + w]); }
    __syncthreads();
    kloopL<16>(Ai8, ws + W3OFF, kh, sxor, arow, col, acc);
    epilogue(acc, AA, b3, m3, be3, Ap + 1024, lane, wv);
    __syncthreads();                                 // AA complete before L4

    // ---- L4: wave 0 only; out = dot + b4 (r15 verbatim) ----
    if (wv == 0) {
#pragma unroll
        for (int ks = 0; ks < 16; ++ks) {
            u32 aw0 = AA[l31 * 17 + ks], aw1 = AA[(l31 + 32) * 17 + ks];
            v4i af0 = expandpm((aw0 >> kh16) & 0xFFFFu);
            v4i af1 = expandpm((aw1 >> kh16) & 0xFFFFu);
            v4i bf = *(const v4i*)(ws + W4OFF + (size_t)((ks * 2 + kh) * 32 + l31) * 16);
            mfma(acc[0], af0, bf);
            mfma(acc[1], af1, bf);
        }
        asm volatile("s_nop 7\ns_nop 7\ns_nop 7" : "+a"(acc[0]), "+a"(acc[1]));
        const int rAdd = (lane & 32) >> 3;
        if (l31 < DOUT) {
            float pb4 = b4[l31];
#pragma unroll
            for (int f = 0; f < 2; ++f)
#pragma unroll
                for (int rg = 0; rg < 16; ++rg) {
                    int rowE = f * 32 + (rg & 3) + 8 * (rg >> 2) + rAdd;
                    out[(size_t)(row0 + rowE) * DOUT + l31] =
                        __fadd_rn((float)acc[f][rg], pb4);
                }
        }
    }
}

extern "C" void kernel_launch(void* const* d_in, const int* in_sizes, int n_in,
                              void* d_out, int out_size, void* d_ws, size_t ws_size,
                              hipStream_t stream)
{
    const float* x   = (const float*)d_in[0];
    const float* w1  = (const float*)d_in[1];
    const float* b1  = (const float*)d_in[2];
    const float* g1  = (const float*)d_in[3];
    const float* be1 = (const float*)d_in[4];
    const float* m1  = (const float*)d_in[5];
    const float* v1  = (const float*)d_in[6];
    const float* w2  = (const float*)d_in[7];
    const float* b2  = (const float*)d_in[8];
    const float* g2  = (const float*)d_in[9];
    const float* be2 = (const float*)d_in[10];
    const float* m2  = (const float*)d_in[11];
    const float* v2  = (const float*)d_in[12];
    const float* w3  = (const float*)d_in[13];
    const float* b3  = (const float*)d_in[14];
    const float* g3  = (const float*)d_in[15];
    const float* be3 = (const float*)d_in[16];
    const float* m3  = (const float*)d_in[17];
    const float* v3  = (const float*)d_in[18];
    const float* w4  = (const float*)d_in[19];
    const float* b4  = (const float*)d_in[20];
    float* out = (float*)d_out;
    char* ws = (char*)d_ws;                 // ~956 KB used

    // weights + Apre only: 59392+1536 threads -> 238 blocks of 256
    bmlp_pack<<<dim3(238), 256, 0, stream>>>(
        w1, w2, w3, w4, g1, v1, g2, v2, g3, v3, ws);

    bmlp_direct<<<dim3(NB / MB), 1024, 0, stream>>>(
        x, ws,
        b1, m1, be1,
        b2, m2, be2,
        b3, m3, be3,
        b4, out);
}